// Round 1
// baseline (1222.815 us; speedup 1.0000x reference)
//
#include <hip/hip_runtime.h>
#include <cstdint>

// Problem constants
// B=2, N=512, CS=256, CZ=128, C=128, H=8, PQK=8, PV=12
// NROWS = H*C (q) + 2*H*C (kv) + H*PQK*3 (qp) + H*(PQK+PV)*3 (kvp) = 1024+2048+192+480 = 3744
// feats dim = 1024 (o) + 288 (o_pt_flat) + 96 (o_pt_norm) + 1024 (o_pair) = 2432

#define NROWS 3744
#define FEATS 2432

// workspace layout (floats)
constexpr size_t OFF_RAW  = 0;                    // 1024*3744 = 3,833,856 ; feats (1024*2432) aliases this
constexpr size_t OFF_Q    = 3833856;              // 1,048,576
constexpr size_t OFF_K    = OFF_Q + 1048576;
constexpr size_t OFF_V    = OFF_K + 1048576;
constexpr size_t OFF_QP   = OFF_V + 1048576;      // 196,608
constexpr size_t OFF_KP   = OFF_QP + 196608;
constexpr size_t OFF_VP   = OFF_KP + 196608;      // 294,912
constexpr size_t OFF_BIAS = OFF_VP + 294912;      // 4,194,304
constexpr size_t OFF_LG   = OFF_BIAS + 4194304;   // 4,194,304 (softmax in place -> a)
constexpr size_t OFF_PART = OFF_LG + 4194304;     // 8*262,144 = 2,097,152
// total = 18,153,472 floats = 72.6 MB

__device__ __forceinline__ void fma4(float4& acc, float s, const float4& v) {
    acc.x += s * v.x; acc.y += s * v.y; acc.z += s * v.z; acc.w += s * v.w;
}
__device__ __forceinline__ float dot4(const float4& a, const float4& b) {
    return a.x*b.x + a.y*b.y + a.z*b.z + a.w*b.w;
}

// ---------------------------------------------------------------------------
// 1. Projection GEMM: raw[token][row] = s[token][:] . Wcat[row][:] + bcat[row]
//    Wcat = [wq (1024); wkv (2048); wqp (192); wkvp (480)] , K = 256
//    grid 480 = 16 token-tiles (64 tokens) x 30 row-groups (128 rows)
// ---------------------------------------------------------------------------
__global__ __launch_bounds__(256) void proj_gemm(
    const float* __restrict__ s,
    const float* __restrict__ wq,  const float* __restrict__ bq,
    const float* __restrict__ wkv, const float* __restrict__ bkv,
    const float* __restrict__ wqp, const float* __restrict__ bqp,
    const float* __restrict__ wkvp,const float* __restrict__ bkvp,
    float* __restrict__ raw)
{
    const int tile = blockIdx.x & 15;
    const int grp  = blockIdx.x >> 4;
    const int bn0  = tile * 64;
    const int r0   = grp * 128;
    __shared__ float s_lds[64 * 33];
    __shared__ float w_lds[128 * 33];
    const int t  = threadIdx.x;
    const int rg = t & 31;   // row lane (owns rows rg, rg+32, rg+64, rg+96)
    const int tg = t >> 5;   // token group (owns tokens tg*8 .. tg*8+7)

    float acc[4][8];
#pragma unroll
    for (int q = 0; q < 4; ++q)
#pragma unroll
        for (int w = 0; w < 8; ++w) acc[q][w] = 0.f;

    for (int kt = 0; kt < 8; ++kt) {
        const int fb = kt * 32;
        __syncthreads();
        for (int idx = t; idx < 64 * 32; idx += 256) {
            int il = idx >> 5, f = idx & 31;
            s_lds[il * 33 + f] = s[(size_t)(bn0 + il) * 256 + fb + f];
        }
        for (int idx = t; idx < 128 * 32; idx += 256) {
            int r = idx >> 5, f = idx & 31;
            int row = r0 + r;
            int ff = fb + f;
            float wv = 0.f;
            if (row < 1024)       wv = wq  [(size_t)row * 256 + ff];
            else if (row < 3072)  wv = wkv [(size_t)(row - 1024) * 256 + ff];
            else if (row < 3264)  wv = wqp [(size_t)(row - 3072) * 256 + ff];
            else if (row < 3744)  wv = wkvp[(size_t)(row - 3264) * 256 + ff];
            w_lds[r * 33 + f] = wv;
        }
        __syncthreads();
#pragma unroll
        for (int f = 0; f < 32; ++f) {
            float wv[4], sv[8];
#pragma unroll
            for (int q = 0; q < 4; ++q) wv[q] = w_lds[(rg + 32 * q) * 33 + f];
#pragma unroll
            for (int w = 0; w < 8; ++w) sv[w] = s_lds[(tg * 8 + w) * 33 + f];
#pragma unroll
            for (int q = 0; q < 4; ++q)
#pragma unroll
                for (int w = 0; w < 8; ++w) acc[q][w] += wv[q] * sv[w];
        }
    }
#pragma unroll
    for (int q = 0; q < 4; ++q) {
        int row = r0 + rg + 32 * q;
        if (row >= NROWS) continue;
        float bv;
        if (row < 1024)      bv = bq  [row];
        else if (row < 3072) bv = bkv [row - 1024];
        else if (row < 3264) bv = bqp [row - 3072];
        else                 bv = bkvp[row - 3264];
#pragma unroll
        for (int w = 0; w < 8; ++w)
            raw[(size_t)(bn0 + tg * 8 + w) * NROWS + row] = acc[q][w] + bv;
    }
}

// ---------------------------------------------------------------------------
// 2. Post: per token, RoPE on q/k, rigid transform on points, scatter to
//    consumer-friendly layouts. grid = 1024 tokens.
//    q,k,v: [b,h,n,128] ; qp,kp: [b,h,n,24] ; vp: [b,h,n,36]
// ---------------------------------------------------------------------------
__global__ __launch_bounds__(256) void post_k(
    const float* __restrict__ raw, const float* __restrict__ rot,
    const float* __restrict__ trans,
    float* __restrict__ q, float* __restrict__ k, float* __restrict__ v,
    float* __restrict__ qp, float* __restrict__ kp, float* __restrict__ vp)
{
    const int bn = blockIdx.x;
    const int b = bn >> 9, n = bn & 511;
    const int t = threadIdx.x;
    __shared__ float r_lds[NROWS];
    for (int idx = t; idx < NROWS; idx += 256)
        r_lds[idx] = raw[(size_t)bn * NROWS + idx];
    __syncthreads();

    const float LOG_BASE = 9.210340371976184f; // ln(10000)

    // q with RoPE (rows 0..1023)
    for (int idx = t; idx < 1024; idx += 256) {
        int h = idx >> 7, c = idx & 127;
        int d = c & 63;
        float inv = expf(-(2.f * d / 128.f) * LOG_BASE);
        float sn, cs; sincosf((float)n * inv, &sn, &cs);
        float val = r_lds[idx];
        float pt  = (c < 64) ? -r_lds[idx + 64] : r_lds[idx - 64];
        q[(((size_t)(b * 8 + h)) * 512 + n) * 128 + c] = val * cs + pt * sn;
    }
    // k (RoPE) / v (rows 1024..3071, per head: 128 k then 128 v)
    for (int idx = t; idx < 2048; idx += 256) {
        int h = idx >> 8, w = idx & 255;
        float val = r_lds[1024 + idx];
        if (w < 128) {
            int c = w, d = c & 63;
            float inv = expf(-(2.f * d / 128.f) * LOG_BASE);
            float sn, cs; sincosf((float)n * inv, &sn, &cs);
            float pt = (c < 64) ? -r_lds[1024 + h * 256 + c + 64]
                                :  r_lds[1024 + h * 256 + c - 64];
            k[(((size_t)(b * 8 + h)) * 512 + n) * 128 + c] = val * cs + pt * sn;
        } else {
            v[(((size_t)(b * 8 + h)) * 512 + n) * 128 + (w - 128)] = val;
        }
    }
    // points
    float R[9], T[3];
#pragma unroll
    for (int u = 0; u < 9; ++u) R[u] = rot[(size_t)bn * 9 + u];
#pragma unroll
    for (int u = 0; u < 3; ++u) T[u] = trans[(size_t)bn * 3 + u];

    if (t < 64) {  // q points: rows 3072 + j*64 + p
        int p = t;
        float x0 = r_lds[3072 + p], x1 = r_lds[3072 + 64 + p], x2 = r_lds[3072 + 128 + p];
        int h = p >> 3, pq = p & 7;
        size_t base = (((size_t)(b * 8 + h)) * 512 + n) * 24 + pq * 3;
        qp[base + 0] = R[0]*x0 + R[1]*x1 + R[2]*x2 + T[0];
        qp[base + 1] = R[3]*x0 + R[4]*x1 + R[5]*x2 + T[1];
        qp[base + 2] = R[6]*x0 + R[7]*x1 + R[8]*x2 + T[2];
    }
    if (t < 160) { // kv points: rows 3264 + j*160 + p
        int p = t;
        float x0 = r_lds[3264 + p], x1 = r_lds[3264 + 160 + p], x2 = r_lds[3264 + 320 + p];
        float g0 = R[0]*x0 + R[1]*x1 + R[2]*x2 + T[0];
        float g1 = R[3]*x0 + R[4]*x1 + R[5]*x2 + T[1];
        float g2 = R[6]*x0 + R[7]*x1 + R[8]*x2 + T[2];
        int h = p / 20, pp = p % 20;
        if (pp < 8) {
            size_t base = (((size_t)(b * 8 + h)) * 512 + n) * 24 + pp * 3;
            kp[base + 0] = g0; kp[base + 1] = g1; kp[base + 2] = g2;
        } else {
            size_t base = (((size_t)(b * 8 + h)) * 512 + n) * 36 + (pp - 8) * 3;
            vp[base + 0] = g0; vp[base + 1] = g1; vp[base + 2] = g2;
        }
    }
}

// ---------------------------------------------------------------------------
// 3. Pair bias: bias_t[b,h,i,j] = z[b,i,j,:].wb[h,:] + bb[h]
//    grid 1024 = (b,i). Lane t streams rows j=t and j=t+256 (z read #1).
//    wb is wave-uniform -> scalar loads, accumulators in VGPRs, no LDS.
// ---------------------------------------------------------------------------
__global__ __launch_bounds__(256) void bias_k(
    const float* __restrict__ z, const float* __restrict__ wb,
    const float* __restrict__ bb, float* __restrict__ bias_t)
{
    const int bi = blockIdx.x;
    const int b = bi >> 9, i = bi & 511;
    const int t = threadIdx.x;
    const float4* z0 = (const float4*)(z + ((size_t)bi * 512 + t) * 128);
    const float4* z1 = (const float4*)(z + ((size_t)bi * 512 + t + 256) * 128);
    const float4* wb4 = (const float4*)wb;
    float acc0[8], acc1[8];
#pragma unroll
    for (int h = 0; h < 8; ++h) { acc0[h] = 0.f; acc1[h] = 0.f; }
#pragma unroll 4
    for (int c4 = 0; c4 < 32; ++c4) {
        float4 a4 = z0[c4];
        float4 b4 = z1[c4];
#pragma unroll
        for (int h = 0; h < 8; ++h) {
            float4 w4 = wb4[h * 32 + c4];
            acc0[h] += dot4(a4, w4);
            acc1[h] += dot4(b4, w4);
        }
    }
#pragma unroll
    for (int h = 0; h < 8; ++h) {
        float bv = bb[h];
        size_t base = (((size_t)(b * 8 + h)) * 512 + i) * 512;
        bias_t[base + t]       = acc0[h] + bv;
        bias_t[base + t + 256] = acc1[h] + bv;
    }
}

// ---------------------------------------------------------------------------
// 4. Logits: lg[b,h,i,j] = scale_qk*(q.k) - 0.5*hw*(|qp|^2+|kp|^2) + hw*(qp.kp)
//            + sqrt(1/3)*bias + mask_term
//    Point cross-term folded into one 152-long LDS dot (q row scaled by
//    scale_qk, qp row scaled by hw). grid 2048 = bh(16) x itile(16) x jtile(8)
// ---------------------------------------------------------------------------
#define SCALE_QK 0.05103103630798287f   // sqrt(1/384)
#define SCALE_B  0.5773502691896258f    // sqrt(1/3)
#define HW_SCALE 0.09622504486493764f   // sqrt(1/108)

__global__ __launch_bounds__(256) void logits_k(
    const float* __restrict__ q, const float* __restrict__ k,
    const float* __restrict__ qp, const float* __restrict__ kp,
    const float* __restrict__ mask, const float* __restrict__ hw_in,
    const float* __restrict__ bias_t, float* __restrict__ lg)
{
    const int blk = blockIdx.x;
    const int jt = blk & 7, it = (blk >> 3) & 15, bh = blk >> 7;
    const int b = bh >> 3, h = bh & 7;
    const int i0 = it * 32, j0 = jt * 64;
    const int t = threadIdx.x;
    const float hw = log1pf(expf(hw_in[h])) * HW_SCALE;

    __shared__ float qe[32 * 156];  // [0:128) scaled q, [128:152) hw-scaled qp
    __shared__ float ke[64 * 156];
    __shared__ float Qs[32], Ks[64], Mi[32], Mj[64];

    for (int idx = t; idx < 32 * 128; idx += 256) {
        int il = idx >> 7, c = idx & 127;
        qe[il * 156 + c] = q[((size_t)bh * 512 + i0 + il) * 128 + c] * SCALE_QK;
    }
    for (int idx = t; idx < 32 * 24; idx += 256) {
        int il = idx / 24, e = idx % 24;
        qe[il * 156 + 128 + e] = qp[((size_t)bh * 512 + i0 + il) * 24 + e] * hw;
    }
    for (int idx = t; idx < 64 * 128; idx += 256) {
        int jl = idx >> 7, c = idx & 127;
        ke[jl * 156 + c] = k[((size_t)bh * 512 + j0 + jl) * 128 + c];
    }
    for (int idx = t; idx < 64 * 24; idx += 256) {
        int jl = idx / 24, e = idx % 24;
        ke[jl * 156 + 128 + e] = kp[((size_t)bh * 512 + j0 + jl) * 24 + e];
    }
    if (t < 32) {
        float sum = 0.f;
        for (int e = 0; e < 24; ++e) {
            float vv = qp[((size_t)bh * 512 + i0 + t) * 24 + e];
            sum += vv * vv;
        }
        Qs[t] = sum;
        Mi[t] = mask[b * 512 + i0 + t];
    }
    if (t >= 64 && t < 128) {
        int jl = t - 64;
        float sum = 0.f;
        for (int e = 0; e < 24; ++e) {
            float vv = kp[((size_t)bh * 512 + j0 + jl) * 24 + e];
            sum += vv * vv;
        }
        Ks[jl] = sum;
        Mj[jl] = mask[b * 512 + j0 + jl];
    }
    __syncthreads();

    const int tr = t >> 4, tc = t & 15;     // il = tr, tr+16 ; jl = tc + 16*qq
    float acc[2][4] = {{0.f,0.f,0.f,0.f},{0.f,0.f,0.f,0.f}};
    const float4* qe4 = (const float4*)qe;
    const float4* ke4 = (const float4*)ke;
#pragma unroll 2
    for (int c4 = 0; c4 < 38; ++c4) {
        float4 qa = qe4[tr * 39 + c4];
        float4 qb = qe4[(tr + 16) * 39 + c4];
#pragma unroll
        for (int qq = 0; qq < 4; ++qq) {
            float4 kv = ke4[(tc + 16 * qq) * 39 + c4];
            acc[0][qq] += dot4(qa, kv);
            acc[1][qq] += dot4(qb, kv);
        }
    }
#pragma unroll
    for (int a2 = 0; a2 < 2; ++a2) {
        int il = tr + 16 * a2, i = i0 + il;
#pragma unroll
        for (int qq = 0; qq < 4; ++qq) {
            int jl = tc + 16 * qq, j = j0 + jl;
            float lv = acc[a2][qq] - 0.5f * hw * (Qs[il] + Ks[jl])
                     + SCALE_B * bias_t[((size_t)bh * 512 + i) * 512 + j]
                     + (Mi[il] * Mj[jl] - 1.f) * 100000.f;
            lg[((size_t)bh * 512 + i) * 512 + j] = lv;
        }
    }
}

// ---------------------------------------------------------------------------
// 5. Softmax in place over j. grid 8192 rows, 64 threads (one wave).
// ---------------------------------------------------------------------------
__global__ __launch_bounds__(64) void softmax_k(float* __restrict__ lg)
{
    const size_t row = blockIdx.x;
    float4* p = (float4*)(lg + row * 512);
    const int t = threadIdx.x;
    float4 v0 = p[t], v1 = p[t + 64];
    float m = fmaxf(fmaxf(fmaxf(v0.x, v0.y), fmaxf(v0.z, v0.w)),
                    fmaxf(fmaxf(v1.x, v1.y), fmaxf(v1.z, v1.w)));
#pragma unroll
    for (int off = 32; off; off >>= 1) m = fmaxf(m, __shfl_xor(m, off));
    v0.x = expf(v0.x - m); v0.y = expf(v0.y - m); v0.z = expf(v0.z - m); v0.w = expf(v0.w - m);
    v1.x = expf(v1.x - m); v1.y = expf(v1.y - m); v1.z = expf(v1.z - m); v1.w = expf(v1.w - m);
    float s = v0.x + v0.y + v0.z + v0.w + v1.x + v1.y + v1.z + v1.w;
#pragma unroll
    for (int off = 32; off; off >>= 1) s += __shfl_xor(s, off);
    float inv = 1.f / s;
    v0.x *= inv; v0.y *= inv; v0.z *= inv; v0.w *= inv;
    v1.x *= inv; v1.y *= inv; v1.z *= inv; v1.w *= inv;
    p[t] = v0; p[t + 64] = v1;
}

// ---------------------------------------------------------------------------
// 6. o = a@v and o_pt = a@v_pts (+ inverse rigid + norms), fused.
//    grid 512 = bh(16) x itile16(32). Thread: c4 = t&31, ig = t>>5 -> 2 rows.
// ---------------------------------------------------------------------------
__global__ __launch_bounds__(256) void av_k(
    const float* __restrict__ a, const float* __restrict__ v,
    const float* __restrict__ vp, const float* __restrict__ rot,
    const float* __restrict__ trans, float* __restrict__ feats)
{
    const int blk = blockIdx.x;
    const int it = blk & 31, bh = blk >> 5;
    const int b = bh >> 3, h = bh & 7;
    const int i0 = it * 16;
    const int t = threadIdx.x;
    const int c4 = t & 31, ig = t >> 5;
    const int ia = i0 + ig * 2, ib = ia + 1;

    const float* ar0 = a + ((size_t)bh * 512 + ia) * 512;
    const float* ar1 = a + ((size_t)bh * 512 + ib) * 512;
    const float4* v4  = (const float4*)(v  + (size_t)bh * 512 * 128);
    const float4* vp4 = (const float4*)(vp + (size_t)bh * 512 * 36);

    float4 acc0 = {0,0,0,0}, acc1 = {0,0,0,0};
    float4 accp0 = {0,0,0,0}, accp1 = {0,0,0,0};

    for (int jt2 = 0; jt2 < 16; ++jt2) {
        const float4* ap0 = (const float4*)(ar0 + jt2 * 32);
        const float4* ap1 = (const float4*)(ar1 + jt2 * 32);
#pragma unroll
        for (int u = 0; u < 8; ++u) {
            float4 a0 = ap0[u];
            float4 a1 = ap1[u];
            int jb = jt2 * 32 + u * 4;
#pragma unroll
            for (int r = 0; r < 4; ++r) {
                float w0 = (r == 0) ? a0.x : (r == 1) ? a0.y : (r == 2) ? a0.z : a0.w;
                float w1 = (r == 0) ? a1.x : (r == 1) ? a1.y : (r == 2) ? a1.z : a1.w;
                float4 vv = v4[(size_t)(jb + r) * 32 + c4];
                fma4(acc0, w0, vv);
                fma4(acc1, w1, vv);
                if (c4 < 9) {
                    float4 pv = vp4[(size_t)(jb + r) * 9 + c4];
                    fma4(accp0, w0, pv);
                    fma4(accp1, w1, pv);
                }
            }
        }
    }
    // o writes
    {
        float4* fo0 = (float4*)(feats + (size_t)(b * 512 + ia) * FEATS + h * 128);
        float4* fo1 = (float4*)(feats + (size_t)(b * 512 + ib) * FEATS + h * 128);
        fo0[c4] = acc0;
        fo1[c4] = acc1;
    }
    // o_pt: stage, rotate back, write flat + norms
    __shared__ float opt_lds[16 * 36];
    if (c4 < 9) {
        int e = c4 * 4;
        float* o0 = &opt_lds[(ig * 2 + 0) * 36 + e];
        o0[0] = accp0.x; o0[1] = accp0.y; o0[2] = accp0.z; o0[3] = accp0.w;
        float* o1 = &opt_lds[(ig * 2 + 1) * 36 + e];
        o1[0] = accp1.x; o1[1] = accp1.y; o1[2] = accp1.z; o1[3] = accp1.w;
    }
    __syncthreads();
    if (t < 192) {
        int il2 = t / 12, p = t % 12;
        int bn = b * 512 + i0 + il2;
        float R[9];
#pragma unroll
        for (int u = 0; u < 9; ++u) R[u] = rot[(size_t)bn * 9 + u];
        float T0 = trans[(size_t)bn * 3 + 0];
        float T1 = trans[(size_t)bn * 3 + 1];
        float T2 = trans[(size_t)bn * 3 + 2];
        float x  = opt_lds[il2 * 36 + p * 3 + 0] - T0;
        float y  = opt_lds[il2 * 36 + p * 3 + 1] - T1;
        float zz = opt_lds[il2 * 36 + p * 3 + 2] - T2;
        float l0 = R[0] * x + R[3] * y + R[6] * zz;  // R^T
        float l1 = R[1] * x + R[4] * y + R[7] * zz;
        float l2 = R[2] * x + R[5] * y + R[8] * zz;
        size_t base = (size_t)bn * FEATS;
        feats[base + 1024 +       h * 12 + p] = l0;
        feats[base + 1024 +  96 + h * 12 + p] = l1;
        feats[base + 1024 + 192 + h * 12 + p] = l2;
        feats[base + 1312 +       h * 12 + p] = sqrtf(l0*l0 + l1*l1 + l2*l2 + 1e-8f);
    }
}

// ---------------------------------------------------------------------------
// 7. o_pair[b,i,h,:] = sum_j a[b,h,i,j] * z[b,i,j,:]  (z read #2)
//    grid 1024 = (b,i), 128 threads: c4 = t&31, hg = t>>5 -> 2 heads each.
// ---------------------------------------------------------------------------
__global__ __launch_bounds__(128) void opair_k(
    const float* __restrict__ a, const float* __restrict__ z,
    float* __restrict__ feats)
{
    const int bi = blockIdx.x;
    const int b = bi >> 9, i = bi & 511;
    const int t = threadIdx.x;
    const int c4 = t & 31, hg = t >> 5;
    const int h0 = hg * 2, h1 = h0 + 1;
    const float* ar0 = a + (((size_t)(b * 8 + h0)) * 512 + i) * 512;
    const float* ar1 = a + (((size_t)(b * 8 + h1)) * 512 + i) * 512;
    const float4* z4 = (const float4*)(z + (size_t)bi * 512 * 128);
    float4 acc0 = {0,0,0,0}, acc1 = {0,0,0,0};

    for (int jt2 = 0; jt2 < 16; ++jt2) {
        const float4* ap0 = (const float4*)(ar0 + jt2 * 32);
        const float4* ap1 = (const float4*)(ar1 + jt2 * 32);
#pragma unroll
        for (int u = 0; u < 8; ++u) {
            float4 a0 = ap0[u];
            float4 a1 = ap1[u];
            int jb = jt2 * 32 + u * 4;
#pragma unroll
            for (int r = 0; r < 4; ++r) {
                float w0 = (r == 0) ? a0.x : (r == 1) ? a0.y : (r == 2) ? a0.z : a0.w;
                float w1 = (r == 0) ? a1.x : (r == 1) ? a1.y : (r == 2) ? a1.z : a1.w;
                float4 zv = z4[(size_t)(jb + r) * 32 + c4];
                fma4(acc0, w0, zv);
                fma4(acc1, w1, zv);
            }
        }
    }
    float4* f0 = (float4*)(feats + (size_t)bi * FEATS + 1408 + h0 * 128);
    float4* f1 = (float4*)(feats + (size_t)bi * FEATS + 1408 + h1 * 128);
    f0[c4] = acc0;
    f1[c4] = acc1;
}

// ---------------------------------------------------------------------------
// 8. Output GEMM (split-K): part[ks][bn][m] = sum_{f in ks-slice} feats.wout
//    grid 256 = 16 token-tiles(64) x 2 m-groups(128) x 8 ksplit(304)
// ---------------------------------------------------------------------------
__global__ __launch_bounds__(256) void out_gemm(
    const float* __restrict__ feats, const float* __restrict__ wout,
    float* __restrict__ part)
{
    const int blk = blockIdx.x;
    const int ks = blk & 7, mg = (blk >> 3) & 1, tile = blk >> 4;
    const int bn0 = tile * 64, m0 = mg * 128, f0 = ks * 304;
    __shared__ float a_lds[64 * 17];
    __shared__ float w_lds[128 * 17];
    const int t = threadIdx.x;
    const int rg = t & 31, tg = t >> 5;
    float acc[4][8];
#pragma unroll
    for (int q = 0; q < 4; ++q)
#pragma unroll
        for (int w = 0; w < 8; ++w) acc[q][w] = 0.f;

    for (int kt = 0; kt < 19; ++kt) {
        const int fb = f0 + kt * 16;
        __syncthreads();
        for (int idx = t; idx < 64 * 16; idx += 256) {
            int il = idx >> 4, f = idx & 15;
            a_lds[il * 17 + f] = feats[(size_t)(bn0 + il) * FEATS + fb + f];
        }
        for (int idx = t; idx < 128 * 16; idx += 256) {
            int r = idx >> 4, f = idx & 15;
            w_lds[r * 17 + f] = wout[(size_t)(m0 + r) * FEATS + fb + f];
        }
        __syncthreads();
#pragma unroll
        for (int f = 0; f < 16; ++f) {
            float wv[4], sv[8];
#pragma unroll
            for (int q = 0; q < 4; ++q) wv[q] = w_lds[(rg + 32 * q) * 17 + f];
#pragma unroll
            for (int w = 0; w < 8; ++w) sv[w] = a_lds[(tg * 8 + w) * 17 + f];
#pragma unroll
            for (int q = 0; q < 4; ++q)
#pragma unroll
                for (int w = 0; w < 8; ++w) acc[q][w] += wv[q] * sv[w];
        }
    }
#pragma unroll
    for (int q = 0; q < 4; ++q)
#pragma unroll
        for (int w = 0; w < 8; ++w)
            part[(size_t)ks * 262144 + (size_t)(bn0 + tg * 8 + w) * 256 + m0 + rg + 32 * q]
                = acc[q][w];
}

// ---------------------------------------------------------------------------
// 9. Reduce split-K partials + bout -> out. 65536 float4's.
// ---------------------------------------------------------------------------
__global__ __launch_bounds__(256) void out_reduce(
    const float* __restrict__ part, const float* __restrict__ bout,
    float* __restrict__ out)
{
    const int idx = blockIdx.x * 256 + threadIdx.x;  // float4 index
    const float4* b4 = (const float4*)bout;
    const float4* p4 = (const float4*)part;
    float4 s = b4[idx & 63];
#pragma unroll
    for (int ksplit = 0; ksplit < 8; ++ksplit) {
        float4 pv = p4[(size_t)ksplit * 65536 + idx];
        s.x += pv.x; s.y += pv.y; s.z += pv.z; s.w += pv.w;
    }
    ((float4*)out)[idx] = s;
}

// ---------------------------------------------------------------------------
extern "C" void kernel_launch(void* const* d_in, const int* in_sizes, int n_in,
                              void* d_out, int out_size, void* d_ws, size_t ws_size,
                              hipStream_t stream)
{
    (void)in_sizes; (void)n_in; (void)out_size; (void)ws_size;
    const float* s     = (const float*)d_in[0];
    const float* z     = (const float*)d_in[1];
    const float* rot   = (const float*)d_in[2];
    const float* trans = (const float*)d_in[3];
    const float* mask  = (const float*)d_in[4];
    const float* wq    = (const float*)d_in[5];
    const float* bq    = (const float*)d_in[6];
    const float* wkv   = (const float*)d_in[7];
    const float* bkv   = (const float*)d_in[8];
    const float* wqp   = (const float*)d_in[9];
    const float* bqp   = (const float*)d_in[10];
    const float* wkvp  = (const float*)d_in[11];
    const float* bkvp  = (const float*)d_in[12];
    const float* wb    = (const float*)d_in[13];
    const float* bb    = (const float*)d_in[14];
    const float* hw    = (const float*)d_in[15];
    const float* wout  = (const float*)d_in[16];
    const float* bout  = (const float*)d_in[17];

    float* ws    = (float*)d_ws;
    float* raw   = ws + OFF_RAW;
    float* qb    = ws + OFF_Q;
    float* kb    = ws + OFF_K;
    float* vb    = ws + OFF_V;
    float* qpb   = ws + OFF_QP;
    float* kpb   = ws + OFF_KP;
    float* vpb   = ws + OFF_VP;
    float* biasb = ws + OFF_BIAS;
    float* lgb   = ws + OFF_LG;
    float* partb = ws + OFF_PART;
    float* featsb = ws + OFF_RAW;   // aliases raw (raw consumed by post_k)

    proj_gemm<<<dim3(480), dim3(256), 0, stream>>>(s, wq, bq, wkv, bkv, wqp, bqp, wkvp, bkvp, raw);
    post_k<<<dim3(1024), dim3(256), 0, stream>>>(raw, rot, trans, qb, kb, vb, qpb, kpb, vpb);
    bias_k<<<dim3(1024), dim3(256), 0, stream>>>(z, wb, bb, biasb);
    logits_k<<<dim3(2048), dim3(256), 0, stream>>>(qb, kb, qpb, kpb, mask, hw, biasb, lgb);
    softmax_k<<<dim3(8192), dim3(64), 0, stream>>>(lgb);
    av_k<<<dim3(512), dim3(256), 0, stream>>>(lgb, vb, vpb, rot, trans, featsb);
    opair_k<<<dim3(1024), dim3(128), 0, stream>>>(lgb, z, featsb);
    out_gemm<<<dim3(256), dim3(256), 0, stream>>>(featsb, wout, partb);
    out_reduce<<<dim3(256), dim3(256), 0, stream>>>(partb, bout, (float*)d_out);
}

// Round 2
// 741.014 us; speedup vs baseline: 1.6502x; 1.6502x over previous
//
#include <hip/hip_runtime.h>
#include <cstdint>

// Problem constants
// B=2, N=512, CS=256, CZ=128, C=128, H=8, PQK=8, PV=12
// NROWS = 1024 (q) + 2048 (kv) + 192 (qp) + 480 (kvp) = 3744
// feats dim = 1024 (o) + 288 (o_pt_flat) + 96 (o_pt_norm) + 1024 (o_pair) = 2432

#define NROWS 3744
#define FEATS 2432

// workspace layout (floats)
constexpr size_t OFF_RAW  = 0;                    // 1024*3744 ; feats aliases this
constexpr size_t OFF_Q    = 3833856;
constexpr size_t OFF_K    = OFF_Q + 1048576;
constexpr size_t OFF_V    = OFF_K + 1048576;
constexpr size_t OFF_QP   = OFF_V + 1048576;
constexpr size_t OFF_KP   = OFF_QP + 196608;
constexpr size_t OFF_VP   = OFF_KP + 196608;
constexpr size_t OFF_BIAS = OFF_VP + 294912;
constexpr size_t OFF_LG   = OFF_BIAS + 4194304;   // raw logits (softmax fused into consumers)
constexpr size_t OFF_PART = OFF_LG + 4194304;

__device__ __forceinline__ void fma4(float4& acc, float s, const float4& v) {
    acc.x += s * v.x; acc.y += s * v.y; acc.z += s * v.z; acc.w += s * v.w;
}
__device__ __forceinline__ float dot4(const float4& a, const float4& b) {
    return a.x*b.x + a.y*b.y + a.z*b.z + a.w*b.w;
}

// ---------------------------------------------------------------------------
// 1. Projection GEMM (unchanged)
// ---------------------------------------------------------------------------
__global__ __launch_bounds__(256) void proj_gemm(
    const float* __restrict__ s,
    const float* __restrict__ wq,  const float* __restrict__ bq,
    const float* __restrict__ wkv, const float* __restrict__ bkv,
    const float* __restrict__ wqp, const float* __restrict__ bqp,
    const float* __restrict__ wkvp,const float* __restrict__ bkvp,
    float* __restrict__ raw)
{
    const int tile = blockIdx.x & 15;
    const int grp  = blockIdx.x >> 4;
    const int bn0  = tile * 64;
    const int r0   = grp * 128;
    __shared__ float s_lds[64 * 33];
    __shared__ float w_lds[128 * 33];
    const int t  = threadIdx.x;
    const int rg = t & 31;
    const int tg = t >> 5;

    float acc[4][8];
#pragma unroll
    for (int q = 0; q < 4; ++q)
#pragma unroll
        for (int w = 0; w < 8; ++w) acc[q][w] = 0.f;

    for (int kt = 0; kt < 8; ++kt) {
        const int fb = kt * 32;
        __syncthreads();
        for (int idx = t; idx < 64 * 32; idx += 256) {
            int il = idx >> 5, f = idx & 31;
            s_lds[il * 33 + f] = s[(size_t)(bn0 + il) * 256 + fb + f];
        }
        for (int idx = t; idx < 128 * 32; idx += 256) {
            int r = idx >> 5, f = idx & 31;
            int row = r0 + r;
            int ff = fb + f;
            float wv = 0.f;
            if (row < 1024)       wv = wq  [(size_t)row * 256 + ff];
            else if (row < 3072)  wv = wkv [(size_t)(row - 1024) * 256 + ff];
            else if (row < 3264)  wv = wqp [(size_t)(row - 3072) * 256 + ff];
            else if (row < 3744)  wv = wkvp[(size_t)(row - 3264) * 256 + ff];
            w_lds[r * 33 + f] = wv;
        }
        __syncthreads();
#pragma unroll
        for (int f = 0; f < 32; ++f) {
            float wv[4], sv[8];
#pragma unroll
            for (int q = 0; q < 4; ++q) wv[q] = w_lds[(rg + 32 * q) * 33 + f];
#pragma unroll
            for (int w = 0; w < 8; ++w) sv[w] = s_lds[(tg * 8 + w) * 33 + f];
#pragma unroll
            for (int q = 0; q < 4; ++q)
#pragma unroll
                for (int w = 0; w < 8; ++w) acc[q][w] += wv[q] * sv[w];
        }
    }
#pragma unroll
    for (int q = 0; q < 4; ++q) {
        int row = r0 + rg + 32 * q;
        if (row >= NROWS) continue;
        float bv;
        if (row < 1024)      bv = bq  [row];
        else if (row < 3072) bv = bkv [row - 1024];
        else if (row < 3264) bv = bqp [row - 3072];
        else                 bv = bkvp[row - 3264];
#pragma unroll
        for (int w = 0; w < 8; ++w)
            raw[(size_t)(bn0 + tg * 8 + w) * NROWS + row] = acc[q][w] + bv;
    }
}

// ---------------------------------------------------------------------------
// 2. Post (unchanged): RoPE + rigid transforms + scatter
// ---------------------------------------------------------------------------
__global__ __launch_bounds__(256) void post_k(
    const float* __restrict__ raw, const float* __restrict__ rot,
    const float* __restrict__ trans,
    float* __restrict__ q, float* __restrict__ k, float* __restrict__ v,
    float* __restrict__ qp, float* __restrict__ kp, float* __restrict__ vp)
{
    const int bn = blockIdx.x;
    const int b = bn >> 9, n = bn & 511;
    const int t = threadIdx.x;
    __shared__ float r_lds[NROWS];
    for (int idx = t; idx < NROWS; idx += 256)
        r_lds[idx] = raw[(size_t)bn * NROWS + idx];
    __syncthreads();

    const float LOG_BASE = 9.210340371976184f; // ln(10000)

    for (int idx = t; idx < 1024; idx += 256) {
        int h = idx >> 7, c = idx & 127;
        int d = c & 63;
        float inv = expf(-(2.f * d / 128.f) * LOG_BASE);
        float sn, cs; sincosf((float)n * inv, &sn, &cs);
        float val = r_lds[idx];
        float pt  = (c < 64) ? -r_lds[idx + 64] : r_lds[idx - 64];
        q[(((size_t)(b * 8 + h)) * 512 + n) * 128 + c] = val * cs + pt * sn;
    }
    for (int idx = t; idx < 2048; idx += 256) {
        int h = idx >> 8, w = idx & 255;
        float val = r_lds[1024 + idx];
        if (w < 128) {
            int c = w, d = c & 63;
            float inv = expf(-(2.f * d / 128.f) * LOG_BASE);
            float sn, cs; sincosf((float)n * inv, &sn, &cs);
            float pt = (c < 64) ? -r_lds[1024 + h * 256 + c + 64]
                                :  r_lds[1024 + h * 256 + c - 64];
            k[(((size_t)(b * 8 + h)) * 512 + n) * 128 + c] = val * cs + pt * sn;
        } else {
            v[(((size_t)(b * 8 + h)) * 512 + n) * 128 + (w - 128)] = val;
        }
    }
    float R[9], T[3];
#pragma unroll
    for (int u = 0; u < 9; ++u) R[u] = rot[(size_t)bn * 9 + u];
#pragma unroll
    for (int u = 0; u < 3; ++u) T[u] = trans[(size_t)bn * 3 + u];

    if (t < 64) {
        int p = t;
        float x0 = r_lds[3072 + p], x1 = r_lds[3072 + 64 + p], x2 = r_lds[3072 + 128 + p];
        int h = p >> 3, pq = p & 7;
        size_t base = (((size_t)(b * 8 + h)) * 512 + n) * 24 + pq * 3;
        qp[base + 0] = R[0]*x0 + R[1]*x1 + R[2]*x2 + T[0];
        qp[base + 1] = R[3]*x0 + R[4]*x1 + R[5]*x2 + T[1];
        qp[base + 2] = R[6]*x0 + R[7]*x1 + R[8]*x2 + T[2];
    }
    if (t < 160) {
        int p = t;
        float x0 = r_lds[3264 + p], x1 = r_lds[3264 + 160 + p], x2 = r_lds[3264 + 320 + p];
        float g0 = R[0]*x0 + R[1]*x1 + R[2]*x2 + T[0];
        float g1 = R[3]*x0 + R[4]*x1 + R[5]*x2 + T[1];
        float g2 = R[6]*x0 + R[7]*x1 + R[8]*x2 + T[2];
        int h = p / 20, pp = p % 20;
        if (pp < 8) {
            size_t base = (((size_t)(b * 8 + h)) * 512 + n) * 24 + pp * 3;
            kp[base + 0] = g0; kp[base + 1] = g1; kp[base + 2] = g2;
        } else {
            size_t base = (((size_t)(b * 8 + h)) * 512 + n) * 36 + (pp - 8) * 3;
            vp[base + 0] = g0; vp[base + 1] = g1; vp[base + 2] = g2;
        }
    }
}

// ---------------------------------------------------------------------------
// 3. Pair bias (unchanged): z read #1
// ---------------------------------------------------------------------------
__global__ __launch_bounds__(256) void bias_k(
    const float* __restrict__ z, const float* __restrict__ wb,
    const float* __restrict__ bb, float* __restrict__ bias_t)
{
    const int bi = blockIdx.x;
    const int b = bi >> 9, i = bi & 511;
    const int t = threadIdx.x;
    const float4* z0 = (const float4*)(z + ((size_t)bi * 512 + t) * 128);
    const float4* z1 = (const float4*)(z + ((size_t)bi * 512 + t + 256) * 128);
    const float4* wb4 = (const float4*)wb;
    float acc0[8], acc1[8];
#pragma unroll
    for (int h = 0; h < 8; ++h) { acc0[h] = 0.f; acc1[h] = 0.f; }
#pragma unroll 4
    for (int c4 = 0; c4 < 32; ++c4) {
        float4 a4 = z0[c4];
        float4 b4 = z1[c4];
#pragma unroll
        for (int h = 0; h < 8; ++h) {
            float4 w4 = wb4[h * 32 + c4];
            acc0[h] += dot4(a4, w4);
            acc1[h] += dot4(b4, w4);
        }
    }
#pragma unroll
    for (int h = 0; h < 8; ++h) {
        float bv = bb[h];
        size_t base = (((size_t)(b * 8 + h)) * 512 + i) * 512;
        bias_t[base + t]       = acc0[h] + bv;
        bias_t[base + t + 256] = acc1[h] + bv;
    }
}

// ---------------------------------------------------------------------------
// 4. Logits (unchanged): writes RAW logits (softmax now fused downstream)
// ---------------------------------------------------------------------------
#define SCALE_QK 0.05103103630798287f   // sqrt(1/384)
#define SCALE_B  0.5773502691896258f    // sqrt(1/3)
#define HW_SCALE 0.09622504486493764f   // sqrt(1/108)

__global__ __launch_bounds__(256) void logits_k(
    const float* __restrict__ q, const float* __restrict__ k,
    const float* __restrict__ qp, const float* __restrict__ kp,
    const float* __restrict__ mask, const float* __restrict__ hw_in,
    const float* __restrict__ bias_t, float* __restrict__ lg)
{
    const int blk = blockIdx.x;
    const int jt = blk & 7, it = (blk >> 3) & 15, bh = blk >> 7;
    const int b = bh >> 3, h = bh & 7;
    const int i0 = it * 32, j0 = jt * 64;
    const int t = threadIdx.x;
    const float hw = log1pf(expf(hw_in[h])) * HW_SCALE;

    __shared__ float qe[32 * 156];
    __shared__ float ke[64 * 156];
    __shared__ float Qs[32], Ks[64], Mi[32], Mj[64];

    for (int idx = t; idx < 32 * 128; idx += 256) {
        int il = idx >> 7, c = idx & 127;
        qe[il * 156 + c] = q[((size_t)bh * 512 + i0 + il) * 128 + c] * SCALE_QK;
    }
    for (int idx = t; idx < 32 * 24; idx += 256) {
        int il = idx / 24, e = idx % 24;
        qe[il * 156 + 128 + e] = qp[((size_t)bh * 512 + i0 + il) * 24 + e] * hw;
    }
    for (int idx = t; idx < 64 * 128; idx += 256) {
        int jl = idx >> 7, c = idx & 127;
        ke[jl * 156 + c] = k[((size_t)bh * 512 + j0 + jl) * 128 + c];
    }
    for (int idx = t; idx < 64 * 24; idx += 256) {
        int jl = idx / 24, e = idx % 24;
        ke[jl * 156 + 128 + e] = kp[((size_t)bh * 512 + j0 + jl) * 24 + e];
    }
    if (t < 32) {
        float sum = 0.f;
        for (int e = 0; e < 24; ++e) {
            float vv = qp[((size_t)bh * 512 + i0 + t) * 24 + e];
            sum += vv * vv;
        }
        Qs[t] = sum;
        Mi[t] = mask[b * 512 + i0 + t];
    }
    if (t >= 64 && t < 128) {
        int jl = t - 64;
        float sum = 0.f;
        for (int e = 0; e < 24; ++e) {
            float vv = kp[((size_t)bh * 512 + j0 + jl) * 24 + e];
            sum += vv * vv;
        }
        Ks[jl] = sum;
        Mj[jl] = mask[b * 512 + j0 + jl];
    }
    __syncthreads();

    const int tr = t >> 4, tc = t & 15;
    float acc[2][4] = {{0.f,0.f,0.f,0.f},{0.f,0.f,0.f,0.f}};
    const float4* qe4 = (const float4*)qe;
    const float4* ke4 = (const float4*)ke;
#pragma unroll 2
    for (int c4 = 0; c4 < 38; ++c4) {
        float4 qa = qe4[tr * 39 + c4];
        float4 qb = qe4[(tr + 16) * 39 + c4];
#pragma unroll
        for (int qq = 0; qq < 4; ++qq) {
            float4 kv = ke4[(tc + 16 * qq) * 39 + c4];
            acc[0][qq] += dot4(qa, kv);
            acc[1][qq] += dot4(qb, kv);
        }
    }
#pragma unroll
    for (int a2 = 0; a2 < 2; ++a2) {
        int il = tr + 16 * a2, i = i0 + il;
#pragma unroll
        for (int qq = 0; qq < 4; ++qq) {
            int jl = tc + 16 * qq, j = j0 + jl;
            float lv = acc[a2][qq] - 0.5f * hw * (Qs[il] + Ks[jl])
                     + SCALE_B * bias_t[((size_t)bh * 512 + i) * 512 + j]
                     + (Mi[il] * Mj[jl] - 1.f) * 100000.f;
            lg[((size_t)bh * 512 + i) * 512 + j] = lv;
        }
    }
}

// ---------------------------------------------------------------------------
// 5. av_k2: fused softmax + o = a@v + o_pt = a@v_pts.
//    Block = (bh, 16 i-rows). 256 threads = 8 j-groups x 32 c4 lanes.
//    Stage raw logits in LDS, softmax in-block, j-parallel accumulate,
//    LDS reduce over j-groups, scale by 1/sum in epilogue.
// ---------------------------------------------------------------------------
__global__ __launch_bounds__(256) void av_k2(
    const float* __restrict__ lg, const float* __restrict__ v,
    const float* __restrict__ vp, const float* __restrict__ rot,
    const float* __restrict__ trans, float* __restrict__ feats)
{
    const int blk = blockIdx.x;            // 512 = bh(16) x it(32)
    const int it = blk & 31, bh = blk >> 5;
    const int b = bh >> 3, h = bh & 7;
    const int i0 = it * 16;
    const int t = threadIdx.x;
    const int jg = t >> 5, c4 = t & 31;

    __shared__ __align__(16) float a_lds[16 * 512];   // 32 KB
    __shared__ __align__(16) float o_red[16 * 128];   // 8 KB
    __shared__ __align__(16) float p_red[16 * 36];    // 2.25 KB
    __shared__ float red[256];
    __shared__ float rmax[16], rinv[16];

    // stage raw logits: 16 rows x 512
    {
        const float4* a4 = (const float4*)(lg + ((size_t)bh * 512 + i0) * 512);
        float4* al4 = (float4*)a_lds;
        for (int idx = t; idx < 16 * 128; idx += 256)
            al4[idx] = a4[idx];
    }
    __syncthreads();

    // softmax stats: 16 rows x 16 threads each, strided j = l + 16u
    {
        const int r = t >> 4, l = t & 15;
        float m = -1e30f;
        for (int u = 0; u < 32; ++u)
            m = fmaxf(m, a_lds[r * 512 + l + 16 * u]);
        red[t] = m;
        __syncthreads();
        if (t < 16) {
            float mm = red[t * 16];
            for (int u = 1; u < 16; ++u) mm = fmaxf(mm, red[t * 16 + u]);
            rmax[t] = mm;
        }
        __syncthreads();
        float rm = rmax[r];
        float sacc = 0.f;
        for (int u = 0; u < 32; ++u) {
            int idx = r * 512 + l + 16 * u;
            float e = __expf(a_lds[idx] - rm);
            a_lds[idx] = e;
            sacc += e;
        }
        red[t] = sacc;
        __syncthreads();
        if (t < 16) {
            float ss = red[t * 16];
            for (int u = 1; u < 16; ++u) ss += red[t * 16 + u];
            rinv[t] = 1.f / ss;
        }
        __syncthreads();
    }

    const int jbase = jg * 64;
    float4 acc[16];

    // pass 1: v
#pragma unroll
    for (int il = 0; il < 16; ++il) acc[il] = {0.f, 0.f, 0.f, 0.f};
    {
        const float4* v4 = (const float4*)(v + (size_t)bh * 512 * 128);
#pragma unroll 2
        for (int jj = 0; jj < 64; jj += 2) {
            int j = jbase + jj;
            float4 v0 = v4[(size_t)j * 32 + c4];
            float4 v1 = v4[(size_t)(j + 1) * 32 + c4];
#pragma unroll
            for (int il = 0; il < 16; ++il) {
                float2 av = *(const float2*)&a_lds[il * 512 + j];
                fma4(acc[il], av.x, v0);
                fma4(acc[il], av.y, v1);
            }
        }
    }
    __syncthreads();
#pragma unroll
    for (int r = 0; r < 8; ++r) {
        if (jg == r) {
#pragma unroll
            for (int il = 0; il < 16; ++il) {
                float4* d = (float4*)&o_red[il * 128 + c4 * 4];
                if (r == 0) *d = acc[il];
                else {
                    float4 cu = *d;
                    cu.x += acc[il].x; cu.y += acc[il].y;
                    cu.z += acc[il].z; cu.w += acc[il].w;
                    *d = cu;
                }
            }
        }
        __syncthreads();
    }

    // pass 2: v_pts (lanes c4 < 9), reuse acc registers
#pragma unroll
    for (int il = 0; il < 16; ++il) acc[il] = {0.f, 0.f, 0.f, 0.f};
    if (c4 < 9) {
        const float4* vp4 = (const float4*)(vp + (size_t)bh * 512 * 36);
#pragma unroll 2
        for (int jj = 0; jj < 64; jj += 2) {
            int j = jbase + jj;
            float4 p0 = vp4[(size_t)j * 9 + c4];
            float4 p1 = vp4[(size_t)(j + 1) * 9 + c4];
#pragma unroll
            for (int il = 0; il < 16; ++il) {
                float2 av = *(const float2*)&a_lds[il * 512 + j];
                fma4(acc[il], av.x, p0);
                fma4(acc[il], av.y, p1);
            }
        }
    }
    __syncthreads();
#pragma unroll
    for (int r = 0; r < 8; ++r) {
        if (jg == r && c4 < 9) {
#pragma unroll
            for (int il = 0; il < 16; ++il) {
                float4* d = (float4*)&p_red[il * 36 + c4 * 4];
                if (r == 0) *d = acc[il];
                else {
                    float4 cu = *d;
                    cu.x += acc[il].x; cu.y += acc[il].y;
                    cu.z += acc[il].z; cu.w += acc[il].w;
                    *d = cu;
                }
            }
        }
        __syncthreads();
    }

    // epilogue: o (scaled by 1/sum)
    for (int idx = t; idx < 16 * 32; idx += 256) {
        int il = idx >> 5;
        float4 val = ((float4*)o_red)[idx];
        float sc = rinv[il];
        val.x *= sc; val.y *= sc; val.z *= sc; val.w *= sc;
        ((float4*)(feats + (size_t)(b * 512 + i0 + il) * FEATS + h * 128))[idx & 31] = val;
    }
    // epilogue: o_pt -> inverse rigid + norms
    if (t < 192) {
        int il2 = t / 12, p = t % 12;
        float sc = rinv[il2];
        int bn = b * 512 + i0 + il2;
        float R[9];
#pragma unroll
        for (int u = 0; u < 9; ++u) R[u] = rot[(size_t)bn * 9 + u];
        float T0 = trans[(size_t)bn * 3 + 0];
        float T1 = trans[(size_t)bn * 3 + 1];
        float T2 = trans[(size_t)bn * 3 + 2];
        float x  = p_red[il2 * 36 + p * 3 + 0] * sc - T0;
        float y  = p_red[il2 * 36 + p * 3 + 1] * sc - T1;
        float zz = p_red[il2 * 36 + p * 3 + 2] * sc - T2;
        float l0 = R[0] * x + R[3] * y + R[6] * zz;  // R^T
        float l1 = R[1] * x + R[4] * y + R[7] * zz;
        float l2 = R[2] * x + R[5] * y + R[8] * zz;
        size_t base = (size_t)bn * FEATS;
        feats[base + 1024 +       h * 12 + p] = l0;
        feats[base + 1024 +  96 + h * 12 + p] = l1;
        feats[base + 1024 + 192 + h * 12 + p] = l2;
        feats[base + 1312 +       h * 12 + p] = sqrtf(l0*l0 + l1*l1 + l2*l2 + 1e-8f);
    }
}

// ---------------------------------------------------------------------------
// 6. opair_k2: fused softmax + o_pair = a@z (z read #2).
//    Block = (b,i). 256 threads = 8 j-groups x 32 c4. Stage 8 heads' raw
//    logit rows, softmax in-block, j-parallel accumulate, reduce, scale.
// ---------------------------------------------------------------------------
__global__ __launch_bounds__(256) void opair_k2(
    const float* __restrict__ lg, const float* __restrict__ z,
    float* __restrict__ feats)
{
    const int bi = blockIdx.x;               // 1024
    const int b = bi >> 9, i = bi & 511;
    const int t = threadIdx.x;
    const int jg = t >> 5, c4 = t & 31;

    __shared__ __align__(16) float a_lds[8 * 512];   // 16 KB
    __shared__ __align__(16) float o_red[8 * 128];   // 4 KB
    __shared__ float red[256];
    __shared__ float rmax[8], rinv[8];

    for (int idx = t; idx < 8 * 128; idx += 256) {
        int h = idx >> 7, jc = idx & 127;
        ((float4*)a_lds)[idx] =
            ((const float4*)(lg + (((size_t)(b * 8 + h)) * 512 + i) * 512))[jc];
    }
    __syncthreads();

    // softmax stats: 8 rows x 32 threads, strided j = l + 32u
    {
        const int r = t >> 5, l = t & 31;
        float m = -1e30f;
        for (int u = 0; u < 16; ++u)
            m = fmaxf(m, a_lds[r * 512 + l + 32 * u]);
        red[t] = m;
        __syncthreads();
        if (t < 8) {
            float mm = red[t * 32];
            for (int u = 1; u < 32; ++u) mm = fmaxf(mm, red[t * 32 + u]);
            rmax[t] = mm;
        }
        __syncthreads();
        float rm = rmax[r];
        float sacc = 0.f;
        for (int u = 0; u < 16; ++u) {
            int idx = r * 512 + l + 32 * u;
            float e = __expf(a_lds[idx] - rm);
            a_lds[idx] = e;
            sacc += e;
        }
        red[t] = sacc;
        __syncthreads();
        if (t < 8) {
            float ss = red[t * 32];
            for (int u = 1; u < 32; ++u) ss += red[t * 32 + u];
            rinv[t] = 1.f / ss;
        }
        __syncthreads();
    }

    const float4* z4 = (const float4*)(z + (size_t)bi * 512 * 128);
    float4 acc[8];
#pragma unroll
    for (int h = 0; h < 8; ++h) acc[h] = {0.f, 0.f, 0.f, 0.f};
    const int jbase = jg * 64;
#pragma unroll 2
    for (int jj = 0; jj < 64; jj += 2) {
        int j = jbase + jj;
        float4 z0 = z4[(size_t)j * 32 + c4];
        float4 z1 = z4[(size_t)(j + 1) * 32 + c4];
#pragma unroll
        for (int h = 0; h < 8; ++h) {
            float2 av = *(const float2*)&a_lds[h * 512 + j];
            fma4(acc[h], av.x, z0);
            fma4(acc[h], av.y, z1);
        }
    }
    __syncthreads();
#pragma unroll
    for (int r = 0; r < 8; ++r) {
        if (jg == r) {
#pragma unroll
            for (int h = 0; h < 8; ++h) {
                float4* d = (float4*)&o_red[h * 128 + c4 * 4];
                if (r == 0) *d = acc[h];
                else {
                    float4 cu = *d;
                    cu.x += acc[h].x; cu.y += acc[h].y;
                    cu.z += acc[h].z; cu.w += acc[h].w;
                    *d = cu;
                }
            }
        }
        __syncthreads();
    }
    {
        int h = t >> 5;
        float4 val = ((float4*)o_red)[t];
        float sc = rinv[h];
        val.x *= sc; val.y *= sc; val.z *= sc; val.w *= sc;
        ((float4*)(feats + (size_t)bi * FEATS + 1408))[t] = val;
    }
}

// ---------------------------------------------------------------------------
// 7. Output GEMM split-K (unchanged)
// ---------------------------------------------------------------------------
__global__ __launch_bounds__(256) void out_gemm(
    const float* __restrict__ feats, const float* __restrict__ wout,
    float* __restrict__ part)
{
    const int blk = blockIdx.x;
    const int ks = blk & 7, mg = (blk >> 3) & 1, tile = blk >> 4;
    const int bn0 = tile * 64, m0 = mg * 128, f0 = ks * 304;
    __shared__ float a_lds[64 * 17];
    __shared__ float w_lds[128 * 17];
    const int t = threadIdx.x;
    const int rg = t & 31, tg = t >> 5;
    float acc[4][8];
#pragma unroll
    for (int q = 0; q < 4; ++q)
#pragma unroll
        for (int w = 0; w < 8; ++w) acc[q][w] = 0.f;

    for (int kt = 0; kt < 19; ++kt) {
        const int fb = f0 + kt * 16;
        __syncthreads();
        for (int idx = t; idx < 64 * 16; idx += 256) {
            int il = idx >> 4, f = idx & 15;
            a_lds[il * 17 + f] = feats[(size_t)(bn0 + il) * FEATS + fb + f];
        }
        for (int idx = t; idx < 128 * 16; idx += 256) {
            int r = idx >> 4, f = idx & 15;
            w_lds[r * 17 + f] = wout[(size_t)(m0 + r) * FEATS + fb + f];
        }
        __syncthreads();
#pragma unroll
        for (int f = 0; f < 16; ++f) {
            float wv[4], sv[8];
#pragma unroll
            for (int q = 0; q < 4; ++q) wv[q] = w_lds[(rg + 32 * q) * 17 + f];
#pragma unroll
            for (int w = 0; w < 8; ++w) sv[w] = a_lds[(tg * 8 + w) * 17 + f];
#pragma unroll
            for (int q = 0; q < 4; ++q)
#pragma unroll
                for (int w = 0; w < 8; ++w) acc[q][w] += wv[q] * sv[w];
        }
    }
#pragma unroll
    for (int q = 0; q < 4; ++q)
#pragma unroll
        for (int w = 0; w < 8; ++w)
            part[(size_t)ks * 262144 + (size_t)(bn0 + tg * 8 + w) * 256 + m0 + rg + 32 * q]
                = acc[q][w];
}

// ---------------------------------------------------------------------------
// 8. Reduce split-K partials + bout -> out (unchanged)
// ---------------------------------------------------------------------------
__global__ __launch_bounds__(256) void out_reduce(
    const float* __restrict__ part, const float* __restrict__ bout,
    float* __restrict__ out)
{
    const int idx = blockIdx.x * 256 + threadIdx.x;
    const float4* b4 = (const float4*)bout;
    const float4* p4 = (const float4*)part;
    float4 s = b4[idx & 63];
#pragma unroll
    for (int ksplit = 0; ksplit < 8; ++ksplit) {
        float4 pv = p4[(size_t)ksplit * 65536 + idx];
        s.x += pv.x; s.y += pv.y; s.z += pv.z; s.w += pv.w;
    }
    ((float4*)out)[idx] = s;
}

// ---------------------------------------------------------------------------
extern "C" void kernel_launch(void* const* d_in, const int* in_sizes, int n_in,
                              void* d_out, int out_size, void* d_ws, size_t ws_size,
                              hipStream_t stream)
{
    (void)in_sizes; (void)n_in; (void)out_size; (void)ws_size;
    const float* s     = (const float*)d_in[0];
    const float* z     = (const float*)d_in[1];
    const float* rot   = (const float*)d_in[2];
    const float* trans = (const float*)d_in[3];
    const float* mask  = (const float*)d_in[4];
    const float* wq    = (const float*)d_in[5];
    const float* bq    = (const float*)d_in[6];
    const float* wkv   = (const float*)d_in[7];
    const float* bkv   = (const float*)d_in[8];
    const float* wqp   = (const float*)d_in[9];
    const float* bqp   = (const float*)d_in[10];
    const float* wkvp  = (const float*)d_in[11];
    const float* bkvp  = (const float*)d_in[12];
    const float* wb    = (const float*)d_in[13];
    const float* bb    = (const float*)d_in[14];
    const float* hw    = (const float*)d_in[15];
    const float* wout  = (const float*)d_in[16];
    const float* bout  = (const float*)d_in[17];

    float* ws    = (float*)d_ws;
    float* raw   = ws + OFF_RAW;
    float* qb    = ws + OFF_Q;
    float* kb    = ws + OFF_K;
    float* vb    = ws + OFF_V;
    float* qpb   = ws + OFF_QP;
    float* kpb   = ws + OFF_KP;
    float* vpb   = ws + OFF_VP;
    float* biasb = ws + OFF_BIAS;
    float* lgb   = ws + OFF_LG;
    float* partb = ws + OFF_PART;
    float* featsb = ws + OFF_RAW;   // aliases raw (consumed by post_k)

    proj_gemm<<<dim3(480), dim3(256), 0, stream>>>(s, wq, bq, wkv, bkv, wqp, bqp, wkvp, bkvp, raw);
    post_k<<<dim3(1024), dim3(256), 0, stream>>>(raw, rot, trans, qb, kb, vb, qpb, kpb, vpb);
    bias_k<<<dim3(1024), dim3(256), 0, stream>>>(z, wb, bb, biasb);
    logits_k<<<dim3(2048), dim3(256), 0, stream>>>(qb, kb, qpb, kpb, mask, hw, biasb, lgb);
    av_k2<<<dim3(512), dim3(256), 0, stream>>>(lgb, vb, vpb, rot, trans, featsb);
    opair_k2<<<dim3(1024), dim3(256), 0, stream>>>(lgb, z, featsb);
    out_gemm<<<dim3(256), dim3(256), 0, stream>>>(featsb, wout, partb);
    out_reduce<<<dim3(256), dim3(256), 0, stream>>>(partb, bout, (float*)d_out);
}

// Round 3
// 707.068 us; speedup vs baseline: 1.7294x; 1.0480x over previous
//
#include <hip/hip_runtime.h>
#include <cstdint>

// Problem constants
// B=2, N=512, CS=256, CZ=128, C=128, H=8, PQK=8, PV=12
// NROWS = 1024 (q) + 2048 (kv) + 192 (qp) + 480 (kvp) = 3744
// feats dim = 1024 (o) + 288 (o_pt_flat) + 96 (o_pt_norm) + 1024 (o_pair) = 2432

#define NROWS 3744
#define FEATS 2432

// workspace layout (floats)
constexpr size_t OFF_RAW  = 0;                    // 1024*3744 ; feats aliases this
constexpr size_t OFF_Q    = 3833856;
constexpr size_t OFF_K    = OFF_Q + 1048576;
constexpr size_t OFF_V    = OFF_K + 1048576;
constexpr size_t OFF_QP   = OFF_V + 1048576;
constexpr size_t OFF_KP   = OFF_QP + 196608;
constexpr size_t OFF_VP   = OFF_KP + 196608;
constexpr size_t OFF_BIAS = OFF_VP + 294912;
constexpr size_t OFF_LG   = OFF_BIAS + 4194304;   // raw logits (softmax fused into consumers)
constexpr size_t OFF_PART = OFF_LG + 4194304;

__device__ __forceinline__ void fma4(float4& acc, float s, const float4& v) {
    acc.x += s * v.x; acc.y += s * v.y; acc.z += s * v.z; acc.w += s * v.w;
}
__device__ __forceinline__ float dot4(const float4& a, const float4& b) {
    return a.x*b.x + a.y*b.y + a.z*b.z + a.w*b.w;
}

// ---------------------------------------------------------------------------
// 1. Projection GEMM — float4 dot-product inner loop.
//    raw[token][row] = s[token][:] . Wcat[row][:] + bcat[row], K=256.
//    grid 480 = 16 token-tiles(64) x 30 row-groups(128).
//    LDS rows padded to 36 floats (9 float4) -> conflict-free b128 reads.
// ---------------------------------------------------------------------------
__global__ __launch_bounds__(256) void proj_gemm(
    const float* __restrict__ s,
    const float* __restrict__ wq,  const float* __restrict__ bq,
    const float* __restrict__ wkv, const float* __restrict__ bkv,
    const float* __restrict__ wqp, const float* __restrict__ bqp,
    const float* __restrict__ wkvp,const float* __restrict__ bkvp,
    float* __restrict__ raw)
{
    const int tile = blockIdx.x & 15;
    const int grp  = blockIdx.x >> 4;
    const int bn0  = tile * 64;
    const int r0   = grp * 128;
    __shared__ __align__(16) float s_lds[64 * 36];
    __shared__ __align__(16) float w_lds[128 * 36];
    const int t  = threadIdx.x;
    const int rg = t & 31;   // rows rg, rg+32, rg+64, rg+96
    const int tg = t >> 5;   // tokens tg*8 .. tg*8+7

    float acc[4][8];
#pragma unroll
    for (int q = 0; q < 4; ++q)
#pragma unroll
        for (int w = 0; w < 8; ++w) acc[q][w] = 0.f;

    for (int kt = 0; kt < 8; ++kt) {
        const int fb = kt * 32;
        __syncthreads();
        // stage s chunk 64x32 (float4)
        for (int idx = t; idx < 64 * 8; idx += 256) {
            int il = idx >> 3, f4i = idx & 7;
            ((float4*)(s_lds + il * 36))[f4i] =
                ((const float4*)(s + (size_t)(bn0 + il) * 256 + fb))[f4i];
        }
        // stage w chunk 128x32 (float4, piecewise source)
        for (int idx = t; idx < 128 * 8; idx += 256) {
            int r = idx >> 3, f4i = idx & 7;
            int row = r0 + r;
            float4 wv = {0.f, 0.f, 0.f, 0.f};
            if (row < 1024)       wv = ((const float4*)(wq   + (size_t)row * 256 + fb))[f4i];
            else if (row < 3072)  wv = ((const float4*)(wkv  + (size_t)(row - 1024) * 256 + fb))[f4i];
            else if (row < 3264)  wv = ((const float4*)(wqp  + (size_t)(row - 3072) * 256 + fb))[f4i];
            else if (row < 3744)  wv = ((const float4*)(wkvp + (size_t)(row - 3264) * 256 + fb))[f4i];
            ((float4*)(w_lds + r * 36))[f4i] = wv;
        }
        __syncthreads();
        const float4* w4p = (const float4*)w_lds;
        const float4* s4p = (const float4*)s_lds;
#pragma unroll
        for (int f4i = 0; f4i < 8; ++f4i) {
            float4 wv[4], sv[8];
#pragma unroll
            for (int q = 0; q < 4; ++q) wv[q] = w4p[(rg + 32 * q) * 9 + f4i];
#pragma unroll
            for (int w = 0; w < 8; ++w) sv[w] = s4p[(tg * 8 + w) * 9 + f4i];
#pragma unroll
            for (int q = 0; q < 4; ++q)
#pragma unroll
                for (int w = 0; w < 8; ++w) acc[q][w] += dot4(wv[q], sv[w]);
        }
    }
#pragma unroll
    for (int q = 0; q < 4; ++q) {
        int row = r0 + rg + 32 * q;
        if (row >= NROWS) continue;
        float bv;
        if (row < 1024)      bv = bq  [row];
        else if (row < 3072) bv = bkv [row - 1024];
        else if (row < 3264) bv = bqp [row - 3072];
        else                 bv = bkvp[row - 3264];
#pragma unroll
        for (int w = 0; w < 8; ++w)
            raw[(size_t)(bn0 + tg * 8 + w) * NROWS + row] = acc[q][w] + bv;
    }
}

// ---------------------------------------------------------------------------
// 2. Post: RoPE via 64-entry LDS sincos table + rigid transforms + scatter.
// ---------------------------------------------------------------------------
__global__ __launch_bounds__(256) void post_k(
    const float* __restrict__ raw, const float* __restrict__ rot,
    const float* __restrict__ trans,
    float* __restrict__ q, float* __restrict__ k, float* __restrict__ v,
    float* __restrict__ qp, float* __restrict__ kp, float* __restrict__ vp)
{
    const int bn = blockIdx.x;
    const int b = bn >> 9, n = bn & 511;
    const int t = threadIdx.x;
    __shared__ float r_lds[NROWS];
    __shared__ float ct[64], st[64];
    for (int idx = t; idx < NROWS; idx += 256)
        r_lds[idx] = raw[(size_t)bn * NROWS + idx];
    if (t < 64) {
        const float LOG_BASE = 9.210340371976184f; // ln(10000)
        float inv = expf(-((float)t / 64.f) * LOG_BASE);
        float sn, cs; sincosf((float)n * inv, &sn, &cs);
        ct[t] = cs; st[t] = sn;
    }
    __syncthreads();

    // q with RoPE (rows 0..1023)
    for (int idx = t; idx < 1024; idx += 256) {
        int c = idx & 127, d = c & 63;
        float val = r_lds[idx];
        float pt  = (c < 64) ? -r_lds[idx + 64] : r_lds[idx - 64];
        int h = idx >> 7;
        q[(((size_t)(b * 8 + h)) * 512 + n) * 128 + c] = val * ct[d] + pt * st[d];
    }
    // k (RoPE) / v (rows 1024..3071, per head: 128 k then 128 v)
    for (int idx = t; idx < 2048; idx += 256) {
        int h = idx >> 8, w = idx & 255;
        float val = r_lds[1024 + idx];
        if (w < 128) {
            int c = w, d = c & 63;
            float pt = (c < 64) ? -r_lds[1024 + h * 256 + c + 64]
                                :  r_lds[1024 + h * 256 + c - 64];
            k[(((size_t)(b * 8 + h)) * 512 + n) * 128 + c] = val * ct[d] + pt * st[d];
        } else {
            v[(((size_t)(b * 8 + h)) * 512 + n) * 128 + (w - 128)] = val;
        }
    }
    float R[9], T[3];
#pragma unroll
    for (int u = 0; u < 9; ++u) R[u] = rot[(size_t)bn * 9 + u];
#pragma unroll
    for (int u = 0; u < 3; ++u) T[u] = trans[(size_t)bn * 3 + u];

    if (t < 64) {
        int p = t;
        float x0 = r_lds[3072 + p], x1 = r_lds[3072 + 64 + p], x2 = r_lds[3072 + 128 + p];
        int h = p >> 3, pq = p & 7;
        size_t base = (((size_t)(b * 8 + h)) * 512 + n) * 24 + pq * 3;
        qp[base + 0] = R[0]*x0 + R[1]*x1 + R[2]*x2 + T[0];
        qp[base + 1] = R[3]*x0 + R[4]*x1 + R[5]*x2 + T[1];
        qp[base + 2] = R[6]*x0 + R[7]*x1 + R[8]*x2 + T[2];
    }
    if (t < 160) {
        int p = t;
        float x0 = r_lds[3264 + p], x1 = r_lds[3264 + 160 + p], x2 = r_lds[3264 + 320 + p];
        float g0 = R[0]*x0 + R[1]*x1 + R[2]*x2 + T[0];
        float g1 = R[3]*x0 + R[4]*x1 + R[5]*x2 + T[1];
        float g2 = R[6]*x0 + R[7]*x1 + R[8]*x2 + T[2];
        int h = p / 20, pp = p % 20;
        if (pp < 8) {
            size_t base = (((size_t)(b * 8 + h)) * 512 + n) * 24 + pp * 3;
            kp[base + 0] = g0; kp[base + 1] = g1; kp[base + 2] = g2;
        } else {
            size_t base = (((size_t)(b * 8 + h)) * 512 + n) * 36 + (pp - 8) * 3;
            vp[base + 0] = g0; vp[base + 1] = g1; vp[base + 2] = g2;
        }
    }
}

// ---------------------------------------------------------------------------
// 3. Pair bias: grid 2048 = (b,i,jhalf); one z-row stream per thread
//    (32 KB/wave L1 footprint, 8 blocks/CU for latency hiding).
// ---------------------------------------------------------------------------
__global__ __launch_bounds__(256) void bias_k(
    const float* __restrict__ z, const float* __restrict__ wb,
    const float* __restrict__ bb, float* __restrict__ bias_t)
{
    const int blk = blockIdx.x;
    const int half = blk & 1;
    const int bi = blk >> 1;
    const int b = bi >> 9, i = bi & 511;
    const int t = threadIdx.x;
    const int j = half * 256 + t;
    const float4* z0 = (const float4*)(z + ((size_t)bi * 512 + j) * 128);
    const float4* wb4 = (const float4*)wb;
    float acc0[8];
#pragma unroll
    for (int h = 0; h < 8; ++h) acc0[h] = 0.f;
#pragma unroll 8
    for (int c4 = 0; c4 < 32; ++c4) {
        float4 a4 = z0[c4];
#pragma unroll
        for (int h = 0; h < 8; ++h)
            acc0[h] += dot4(a4, wb4[h * 32 + c4]);
    }
#pragma unroll
    for (int h = 0; h < 8; ++h) {
        size_t base = (((size_t)(b * 8 + h)) * 512 + i) * 512;
        bias_t[base + j] = acc0[h] + bb[h];
    }
}

// ---------------------------------------------------------------------------
// 4. Logits (unchanged): writes RAW logits
// ---------------------------------------------------------------------------
#define SCALE_QK 0.05103103630798287f   // sqrt(1/384)
#define SCALE_B  0.5773502691896258f    // sqrt(1/3)
#define HW_SCALE 0.09622504486493764f   // sqrt(1/108)

__global__ __launch_bounds__(256) void logits_k(
    const float* __restrict__ q, const float* __restrict__ k,
    const float* __restrict__ qp, const float* __restrict__ kp,
    const float* __restrict__ mask, const float* __restrict__ hw_in,
    const float* __restrict__ bias_t, float* __restrict__ lg)
{
    const int blk = blockIdx.x;
    const int jt = blk & 7, it = (blk >> 3) & 15, bh = blk >> 7;
    const int b = bh >> 3, h = bh & 7;
    const int i0 = it * 32, j0 = jt * 64;
    const int t = threadIdx.x;
    const float hw = log1pf(expf(hw_in[h])) * HW_SCALE;

    __shared__ float qe[32 * 156];
    __shared__ float ke[64 * 156];
    __shared__ float Qs[32], Ks[64], Mi[32], Mj[64];

    for (int idx = t; idx < 32 * 128; idx += 256) {
        int il = idx >> 7, c = idx & 127;
        qe[il * 156 + c] = q[((size_t)bh * 512 + i0 + il) * 128 + c] * SCALE_QK;
    }
    for (int idx = t; idx < 32 * 24; idx += 256) {
        int il = idx / 24, e = idx % 24;
        qe[il * 156 + 128 + e] = qp[((size_t)bh * 512 + i0 + il) * 24 + e] * hw;
    }
    for (int idx = t; idx < 64 * 128; idx += 256) {
        int jl = idx >> 7, c = idx & 127;
        ke[jl * 156 + c] = k[((size_t)bh * 512 + j0 + jl) * 128 + c];
    }
    for (int idx = t; idx < 64 * 24; idx += 256) {
        int jl = idx / 24, e = idx % 24;
        ke[jl * 156 + 128 + e] = kp[((size_t)bh * 512 + j0 + jl) * 24 + e];
    }
    if (t < 32) {
        float sum = 0.f;
        for (int e = 0; e < 24; ++e) {
            float vv = qp[((size_t)bh * 512 + i0 + t) * 24 + e];
            sum += vv * vv;
        }
        Qs[t] = sum;
        Mi[t] = mask[b * 512 + i0 + t];
    }
    if (t >= 64 && t < 128) {
        int jl = t - 64;
        float sum = 0.f;
        for (int e = 0; e < 24; ++e) {
            float vv = kp[((size_t)bh * 512 + j0 + jl) * 24 + e];
            sum += vv * vv;
        }
        Ks[jl] = sum;
        Mj[jl] = mask[b * 512 + j0 + jl];
    }
    __syncthreads();

    const int tr = t >> 4, tc = t & 15;
    float acc[2][4] = {{0.f,0.f,0.f,0.f},{0.f,0.f,0.f,0.f}};
    const float4* qe4 = (const float4*)qe;
    const float4* ke4 = (const float4*)ke;
#pragma unroll 2
    for (int c4 = 0; c4 < 38; ++c4) {
        float4 qa = qe4[tr * 39 + c4];
        float4 qb = qe4[(tr + 16) * 39 + c4];
#pragma unroll
        for (int qq = 0; qq < 4; ++qq) {
            float4 kv = ke4[(tc + 16 * qq) * 39 + c4];
            acc[0][qq] += dot4(qa, kv);
            acc[1][qq] += dot4(qb, kv);
        }
    }
#pragma unroll
    for (int a2 = 0; a2 < 2; ++a2) {
        int il = tr + 16 * a2, i = i0 + il;
#pragma unroll
        for (int qq = 0; qq < 4; ++qq) {
            int jl = tc + 16 * qq, j = j0 + jl;
            float lv = acc[a2][qq] - 0.5f * hw * (Qs[il] + Ks[jl])
                     + SCALE_B * bias_t[((size_t)bh * 512 + i) * 512 + j]
                     + (Mi[il] * Mj[jl] - 1.f) * 100000.f;
            lg[((size_t)bh * 512 + i) * 512 + j] = lv;
        }
    }
}

// ---------------------------------------------------------------------------
// 5. av_k2 (unchanged): fused softmax + o = a@v + o_pt = a@v_pts
// ---------------------------------------------------------------------------
__global__ __launch_bounds__(256) void av_k2(
    const float* __restrict__ lg, const float* __restrict__ v,
    const float* __restrict__ vp, const float* __restrict__ rot,
    const float* __restrict__ trans, float* __restrict__ feats)
{
    const int blk = blockIdx.x;            // 512 = bh(16) x it(32)
    const int it = blk & 31, bh = blk >> 5;
    const int b = bh >> 3, h = bh & 7;
    const int i0 = it * 16;
    const int t = threadIdx.x;
    const int jg = t >> 5, c4 = t & 31;

    __shared__ __align__(16) float a_lds[16 * 512];   // 32 KB
    __shared__ __align__(16) float o_red[16 * 128];   // 8 KB
    __shared__ __align__(16) float p_red[16 * 36];    // 2.25 KB
    __shared__ float red[256];
    __shared__ float rmax[16], rinv[16];

    {
        const float4* a4 = (const float4*)(lg + ((size_t)bh * 512 + i0) * 512);
        float4* al4 = (float4*)a_lds;
        for (int idx = t; idx < 16 * 128; idx += 256)
            al4[idx] = a4[idx];
    }
    __syncthreads();

    {
        const int r = t >> 4, l = t & 15;
        float m = -1e30f;
        for (int u = 0; u < 32; ++u)
            m = fmaxf(m, a_lds[r * 512 + l + 16 * u]);
        red[t] = m;
        __syncthreads();
        if (t < 16) {
            float mm = red[t * 16];
            for (int u = 1; u < 16; ++u) mm = fmaxf(mm, red[t * 16 + u]);
            rmax[t] = mm;
        }
        __syncthreads();
        float rm = rmax[r];
        float sacc = 0.f;
        for (int u = 0; u < 32; ++u) {
            int idx = r * 512 + l + 16 * u;
            float e = __expf(a_lds[idx] - rm);
            a_lds[idx] = e;
            sacc += e;
        }
        red[t] = sacc;
        __syncthreads();
        if (t < 16) {
            float ss = red[t * 16];
            for (int u = 1; u < 16; ++u) ss += red[t * 16 + u];
            rinv[t] = 1.f / ss;
        }
        __syncthreads();
    }

    const int jbase = jg * 64;
    float4 acc[16];

#pragma unroll
    for (int il = 0; il < 16; ++il) acc[il] = {0.f, 0.f, 0.f, 0.f};
    {
        const float4* v4 = (const float4*)(v + (size_t)bh * 512 * 128);
#pragma unroll 2
        for (int jj = 0; jj < 64; jj += 2) {
            int j = jbase + jj;
            float4 v0 = v4[(size_t)j * 32 + c4];
            float4 v1 = v4[(size_t)(j + 1) * 32 + c4];
#pragma unroll
            for (int il = 0; il < 16; ++il) {
                float2 av = *(const float2*)&a_lds[il * 512 + j];
                fma4(acc[il], av.x, v0);
                fma4(acc[il], av.y, v1);
            }
        }
    }
    __syncthreads();
#pragma unroll
    for (int r = 0; r < 8; ++r) {
        if (jg == r) {
#pragma unroll
            for (int il = 0; il < 16; ++il) {
                float4* d = (float4*)&o_red[il * 128 + c4 * 4];
                if (r == 0) *d = acc[il];
                else {
                    float4 cu = *d;
                    cu.x += acc[il].x; cu.y += acc[il].y;
                    cu.z += acc[il].z; cu.w += acc[il].w;
                    *d = cu;
                }
            }
        }
        __syncthreads();
    }

#pragma unroll
    for (int il = 0; il < 16; ++il) acc[il] = {0.f, 0.f, 0.f, 0.f};
    if (c4 < 9) {
        const float4* vp4 = (const float4*)(vp + (size_t)bh * 512 * 36);
#pragma unroll 2
        for (int jj = 0; jj < 64; jj += 2) {
            int j = jbase + jj;
            float4 p0 = vp4[(size_t)j * 9 + c4];
            float4 p1 = vp4[(size_t)(j + 1) * 9 + c4];
#pragma unroll
            for (int il = 0; il < 16; ++il) {
                float2 av = *(const float2*)&a_lds[il * 512 + j];
                fma4(acc[il], av.x, p0);
                fma4(acc[il], av.y, p1);
            }
        }
    }
    __syncthreads();
#pragma unroll
    for (int r = 0; r < 8; ++r) {
        if (jg == r && c4 < 9) {
#pragma unroll
            for (int il = 0; il < 16; ++il) {
                float4* d = (float4*)&p_red[il * 36 + c4 * 4];
                if (r == 0) *d = acc[il];
                else {
                    float4 cu = *d;
                    cu.x += acc[il].x; cu.y += acc[il].y;
                    cu.z += acc[il].z; cu.w += acc[il].w;
                    *d = cu;
                }
            }
        }
        __syncthreads();
    }

    for (int idx = t; idx < 16 * 32; idx += 256) {
        int il = idx >> 5;
        float4 val = ((float4*)o_red)[idx];
        float sc = rinv[il];
        val.x *= sc; val.y *= sc; val.z *= sc; val.w *= sc;
        ((float4*)(feats + (size_t)(b * 512 + i0 + il) * FEATS + h * 128))[idx & 31] = val;
    }
    if (t < 192) {
        int il2 = t / 12, p = t % 12;
        float sc = rinv[il2];
        int bn = b * 512 + i0 + il2;
        float R[9];
#pragma unroll
        for (int u = 0; u < 9; ++u) R[u] = rot[(size_t)bn * 9 + u];
        float T0 = trans[(size_t)bn * 3 + 0];
        float T1 = trans[(size_t)bn * 3 + 1];
        float T2 = trans[(size_t)bn * 3 + 2];
        float x  = p_red[il2 * 36 + p * 3 + 0] * sc - T0;
        float y  = p_red[il2 * 36 + p * 3 + 1] * sc - T1;
        float zz = p_red[il2 * 36 + p * 3 + 2] * sc - T2;
        float l0 = R[0] * x + R[3] * y + R[6] * zz;  // R^T
        float l1 = R[1] * x + R[4] * y + R[7] * zz;
        float l2 = R[2] * x + R[5] * y + R[8] * zz;
        size_t base = (size_t)bn * FEATS;
        feats[base + 1024 +       h * 12 + p] = l0;
        feats[base + 1024 +  96 + h * 12 + p] = l1;
        feats[base + 1024 + 192 + h * 12 + p] = l2;
        feats[base + 1312 +       h * 12 + p] = sqrtf(l0*l0 + l1*l1 + l2*l2 + 1e-8f);
    }
}

// ---------------------------------------------------------------------------
// 6. opair_k2 (unchanged): fused softmax + o_pair = a@z
// ---------------------------------------------------------------------------
__global__ __launch_bounds__(256) void opair_k2(
    const float* __restrict__ lg, const float* __restrict__ z,
    float* __restrict__ feats)
{
    const int bi = blockIdx.x;               // 1024
    const int b = bi >> 9, i = bi & 511;
    const int t = threadIdx.x;
    const int jg = t >> 5, c4 = t & 31;

    __shared__ __align__(16) float a_lds[8 * 512];   // 16 KB
    __shared__ __align__(16) float o_red[8 * 128];   // 4 KB
    __shared__ float red[256];
    __shared__ float rmax[8], rinv[8];

    for (int idx = t; idx < 8 * 128; idx += 256) {
        int h = idx >> 7, jc = idx & 127;
        ((float4*)a_lds)[idx] =
            ((const float4*)(lg + (((size_t)(b * 8 + h)) * 512 + i) * 512))[jc];
    }
    __syncthreads();

    {
        const int r = t >> 5, l = t & 31;
        float m = -1e30f;
        for (int u = 0; u < 16; ++u)
            m = fmaxf(m, a_lds[r * 512 + l + 32 * u]);
        red[t] = m;
        __syncthreads();
        if (t < 8) {
            float mm = red[t * 32];
            for (int u = 1; u < 32; ++u) mm = fmaxf(mm, red[t * 32 + u]);
            rmax[t] = mm;
        }
        __syncthreads();
        float rm = rmax[r];
        float sacc = 0.f;
        for (int u = 0; u < 16; ++u) {
            int idx = r * 512 + l + 32 * u;
            float e = __expf(a_lds[idx] - rm);
            a_lds[idx] = e;
            sacc += e;
        }
        red[t] = sacc;
        __syncthreads();
        if (t < 8) {
            float ss = red[t * 32];
            for (int u = 1; u < 32; ++u) ss += red[t * 32 + u];
            rinv[t] = 1.f / ss;
        }
        __syncthreads();
    }

    const float4* z4 = (const float4*)(z + (size_t)bi * 512 * 128);
    float4 acc[8];
#pragma unroll
    for (int h = 0; h < 8; ++h) acc[h] = {0.f, 0.f, 0.f, 0.f};
    const int jbase = jg * 64;
#pragma unroll 2
    for (int jj = 0; jj < 64; jj += 2) {
        int j = jbase + jj;
        float4 z0 = z4[(size_t)j * 32 + c4];
        float4 z1 = z4[(size_t)(j + 1) * 32 + c4];
#pragma unroll
        for (int h = 0; h < 8; ++h) {
            float2 av = *(const float2*)&a_lds[h * 512 + j];
            fma4(acc[h], av.x, z0);
            fma4(acc[h], av.y, z1);
        }
    }
    __syncthreads();
#pragma unroll
    for (int r = 0; r < 8; ++r) {
        if (jg == r) {
#pragma unroll
            for (int h = 0; h < 8; ++h) {
                float4* d = (float4*)&o_red[h * 128 + c4 * 4];
                if (r == 0) *d = acc[h];
                else {
                    float4 cu = *d;
                    cu.x += acc[h].x; cu.y += acc[h].y;
                    cu.z += acc[h].z; cu.w += acc[h].w;
                    *d = cu;
                }
            }
        }
        __syncthreads();
    }
    {
        int h = t >> 5;
        float4 val = ((float4*)o_red)[t];
        float sc = rinv[h];
        val.x *= sc; val.y *= sc; val.z *= sc; val.w *= sc;
        ((float4*)(feats + (size_t)bi * FEATS + 1408))[t] = val;
    }
}

// ---------------------------------------------------------------------------
// 7. Output GEMM split-K — float4 dot-product inner loop.
//    LDS rows padded to 20 floats (5 float4).
// ---------------------------------------------------------------------------
__global__ __launch_bounds__(256) void out_gemm(
    const float* __restrict__ feats, const float* __restrict__ wout,
    float* __restrict__ part)
{
    const int blk = blockIdx.x;
    const int ks = blk & 7, mg = (blk >> 3) & 1, tile = blk >> 4;
    const int bn0 = tile * 64, m0 = mg * 128, f0 = ks * 304;
    __shared__ __align__(16) float a_lds[64 * 20];
    __shared__ __align__(16) float w_lds[128 * 20];
    const int t = threadIdx.x;
    const int rg = t & 31, tg = t >> 5;
    float acc[4][8];
#pragma unroll
    for (int q = 0; q < 4; ++q)
#pragma unroll
        for (int w = 0; w < 8; ++w) acc[q][w] = 0.f;

    for (int kt = 0; kt < 19; ++kt) {
        const int fb = f0 + kt * 16;
        __syncthreads();
        for (int idx = t; idx < 64 * 4; idx += 256) {
            int il = idx >> 2, f4i = idx & 3;
            ((float4*)(a_lds + il * 20))[f4i] =
                ((const float4*)(feats + (size_t)(bn0 + il) * FEATS + fb))[f4i];
        }
        for (int idx = t; idx < 128 * 4; idx += 256) {
            int r = idx >> 2, f4i = idx & 3;
            ((float4*)(w_lds + r * 20))[f4i] =
                ((const float4*)(wout + (size_t)(m0 + r) * FEATS + fb))[f4i];
        }
        __syncthreads();
        const float4* w4p = (const float4*)w_lds;
        const float4* a4p = (const float4*)a_lds;
#pragma unroll
        for (int f4i = 0; f4i < 4; ++f4i) {
            float4 wv[4], sv[8];
#pragma unroll
            for (int q = 0; q < 4; ++q) wv[q] = w4p[(rg + 32 * q) * 5 + f4i];
#pragma unroll
            for (int w = 0; w < 8; ++w) sv[w] = a4p[(tg * 8 + w) * 5 + f4i];
#pragma unroll
            for (int q = 0; q < 4; ++q)
#pragma unroll
                for (int w = 0; w < 8; ++w) acc[q][w] += dot4(wv[q], sv[w]);
        }
    }
#pragma unroll
    for (int q = 0; q < 4; ++q)
#pragma unroll
        for (int w = 0; w < 8; ++w)
            part[(size_t)ks * 262144 + (size_t)(bn0 + tg * 8 + w) * 256 + m0 + rg + 32 * q]
                = acc[q][w];
}

// ---------------------------------------------------------------------------
// 8. Reduce split-K partials + bout -> out (unchanged)
// ---------------------------------------------------------------------------
__global__ __launch_bounds__(256) void out_reduce(
    const float* __restrict__ part, const float* __restrict__ bout,
    float* __restrict__ out)
{
    const int idx = blockIdx.x * 256 + threadIdx.x;
    const float4* b4 = (const float4*)bout;
    const float4* p4 = (const float4*)part;
    float4 s = b4[idx & 63];
#pragma unroll
    for (int ksplit = 0; ksplit < 8; ++ksplit) {
        float4 pv = p4[(size_t)ksplit * 65536 + idx];
        s.x += pv.x; s.y += pv.y; s.z += pv.z; s.w += pv.w;
    }
    ((float4*)out)[idx] = s;
}

// ---------------------------------------------------------------------------
extern "C" void kernel_launch(void* const* d_in, const int* in_sizes, int n_in,
                              void* d_out, int out_size, void* d_ws, size_t ws_size,
                              hipStream_t stream)
{
    (void)in_sizes; (void)n_in; (void)out_size; (void)ws_size;
    const float* s     = (const float*)d_in[0];
    const float* z     = (const float*)d_in[1];
    const float* rot   = (const float*)d_in[2];
    const float* trans = (const float*)d_in[3];
    const float* mask  = (const float*)d_in[4];
    const float* wq    = (const float*)d_in[5];
    const float* bq    = (const float*)d_in[6];
    const float* wkv   = (const float*)d_in[7];
    const float* bkv   = (const float*)d_in[8];
    const float* wqp   = (const float*)d_in[9];
    const float* bqp   = (const float*)d_in[10];
    const float* wkvp  = (const float*)d_in[11];
    const float* bkvp  = (const float*)d_in[12];
    const float* wb    = (const float*)d_in[13];
    const float* bb    = (const float*)d_in[14];
    const float* hw    = (const float*)d_in[15];
    const float* wout  = (const float*)d_in[16];
    const float* bout  = (const float*)d_in[17];

    float* ws    = (float*)d_ws;
    float* raw   = ws + OFF_RAW;
    float* qb    = ws + OFF_Q;
    float* kb    = ws + OFF_K;
    float* vb    = ws + OFF_V;
    float* qpb   = ws + OFF_QP;
    float* kpb   = ws + OFF_KP;
    float* vpb   = ws + OFF_VP;
    float* biasb = ws + OFF_BIAS;
    float* lgb   = ws + OFF_LG;
    float* partb = ws + OFF_PART;
    float* featsb = ws + OFF_RAW;   // aliases raw (consumed by post_k)

    proj_gemm<<<dim3(480), dim3(256), 0, stream>>>(s, wq, bq, wkv, bkv, wqp, bqp, wkvp, bkvp, raw);
    post_k<<<dim3(1024), dim3(256), 0, stream>>>(raw, rot, trans, qb, kb, vb, qpb, kpb, vpb);
    bias_k<<<dim3(2048), dim3(256), 0, stream>>>(z, wb, bb, biasb);
    logits_k<<<dim3(2048), dim3(256), 0, stream>>>(qb, kb, qpb, kpb, mask, hw, biasb, lgb);
    av_k2<<<dim3(512), dim3(256), 0, stream>>>(lgb, vb, vpb, rot, trans, featsb);
    opair_k2<<<dim3(1024), dim3(256), 0, stream>>>(lgb, z, featsb);
    out_gemm<<<dim3(256), dim3(256), 0, stream>>>(featsb, wout, partb);
    out_reduce<<<dim3(256), dim3(256), 0, stream>>>(partb, bout, (float*)d_out);
}